// Round 1
// 682.693 us; speedup vs baseline: 1.0118x; 1.0118x over previous
//
#include <hip/hip_runtime.h>
#include <math.h>

// MoE: B=2 S=2048 D=1024 E=8 H=4096 K=2
#define Bc 2
#define Sc 2048
#define Dc 1024
#define Ec 8
#define Hc 4096
#define Tc (Bc*Sc)          // 4096 tokens
#define NSLOT (Tc*2)        // 8192 token-expert slots (top-2 always)
#define FINAL_N ((size_t)Tc*Dc)
#define BK 32               // K-panel (bf16 elems) = 64B per row = 4x 16B chunks

typedef float f32x4 __attribute__((ext_vector_type(4)));
typedef __bf16 bf16x8 __attribute__((ext_vector_type(8)));

__device__ __forceinline__ unsigned short f2bf(float f) {
    union { float f; unsigned int u; } v; v.f = f;
    return (unsigned short)((v.u + 0x7fffu + ((v.u >> 16) & 1u)) >> 16);
}

// async global->LDS, 16B per lane. LDS dest = uniform base + lane*16 (linear).
__device__ __forceinline__ void gload16(const unsigned short* g, unsigned short* l) {
    __builtin_amdgcn_global_load_lds(
        (const __attribute__((address_space(1))) unsigned int*)g,
        (__attribute__((address_space(3))) unsigned int*)l,
        16, 0, 0);
}

// raw barrier with compiler fences (NO vmcnt(0) drain, unlike __syncthreads)
__device__ __forceinline__ void fence_bar() {
    __builtin_amdgcn_sched_barrier(0);
    asm volatile("s_barrier" ::: "memory");
    __builtin_amdgcn_sched_barrier(0);
}

// ---------------- x -> bf16 ----------------
__global__ void k_cvt_x(const float* __restrict__ x, unsigned short* __restrict__ xbf) {
    int gid = blockIdx.x * 256 + threadIdx.x;     // Tc*Dc/8 threads
    const float4* p = (const float4*)x + (size_t)gid * 2;
    float4 a = p[0], b = p[1];
    ushort4 r0 = { f2bf(a.x), f2bf(a.y), f2bf(a.z), f2bf(a.w) };
    ushort4 r1 = { f2bf(b.x), f2bf(b.y), f2bf(b.z), f2bf(b.w) };
    ushort4* o = (ushort4*)xbf + (size_t)gid * 2;
    o[0] = r0; o[1] = r1;
}

// ------- [R][C] fp32 -> [C][R] bf16, 64x64 tiles; z selects {matrix, expert} -------
__global__ void k_transpose_cvt2(const float* __restrict__ inA, const float* __restrict__ inB,
                                 unsigned short* __restrict__ outA, unsigned short* __restrict__ outB,
                                 int R, int C, int nz_per_mat) {
    __shared__ float tile[64][65];
    int z = blockIdx.z;
    const float* in; unsigned short* out;
    if (z < nz_per_mat) { in = inA; out = outA; }
    else { in = inB; out = outB; z -= nz_per_mat; }
    size_t base = (size_t)z * (size_t)R * C;
    int cb = blockIdx.x * 64, rb = blockIdx.y * 64;
    int t = threadIdx.x;             // 256
    int q = t & 15, g = t >> 4;
    #pragma unroll
    for (int j = 0; j < 4; j++) {
        int row = g + 16*j;
        float4 v = *(const float4*)&in[base + (size_t)(rb+row)*C + cb + q*4];
        tile[row][q*4+0] = v.x; tile[row][q*4+1] = v.y;
        tile[row][q*4+2] = v.z; tile[row][q*4+3] = v.w;
    }
    __syncthreads();
    #pragma unroll
    for (int j = 0; j < 4; j++) {
        int co = g + 16*j;
        ushort4 o;
        o.x = f2bf(tile[q*4+0][co]); o.y = f2bf(tile[q*4+1][co]);
        o.z = f2bf(tile[q*4+2][co]); o.w = f2bf(tile[q*4+3][co]);
        *(ushort4*)&out[base + (size_t)(cb+co)*R + rb + q*4] = o;
    }
}

// ---------------- gating: one wave per token ----------------
__global__ void k_gate(const float* __restrict__ x, const float* __restrict__ noise,
                       const float* __restrict__ Wg, const float* __restrict__ nw,
                       float* __restrict__ out_idx, int* __restrict__ counts,
                       int* __restrict__ tok_top, float* __restrict__ tok_w) {
    int t = blockIdx.x;
    int lane = threadIdx.x;                     // 64
    const float* xr = x + (size_t)t * Dc;
    double acc[Ec];
    #pragma unroll
    for (int e = 0; e < Ec; e++) acc[e] = 0.0;
    for (int i = 0; i < Dc/64; i++) {
        int d = lane + i*64;
        double xv = (double)xr[d];
        #pragma unroll
        for (int e = 0; e < Ec; e++) acc[e] += xv * (double)Wg[e*Dc + d];
    }
    #pragma unroll
    for (int e = 0; e < Ec; e++)
        for (int off = 32; off > 0; off >>= 1)
            acc[e] += __shfl_down(acc[e], off);
    if (lane == 0) {
        double noisy[Ec];
        #pragma unroll
        for (int e = 0; e < Ec; e++)
            noisy[e] = acc[e] + (double)noise[t*Ec + e] * (double)nw[e];
        int i0 = 0;
        for (int e = 1; e < Ec; e++) if (noisy[e] > noisy[i0]) i0 = e;   // ties -> lowest idx
        int i1 = -1;
        for (int e = 0; e < Ec; e++) {
            if (e == i0) continue;
            if (i1 < 0 || noisy[e] > noisy[i1]) i1 = e;
        }
        double ee = exp(noisy[i1] - noisy[i0]);   // v1 <= v0, stable
        float w0 = (float)(1.0 / (1.0 + ee));
        float w1 = (float)(ee / (1.0 + ee));
        out_idx[t*2 + 0] = (float)i0;
        out_idx[t*2 + 1] = (float)i1;
        tok_top[t*2] = i0; tok_top[t*2+1] = i1;
        tok_w[t*2] = w0;   tok_w[t*2+1] = w1;
        atomicAdd(&counts[i0], 1);
        atomicAdd(&counts[i1], 1);
    }
}

__global__ void k_scan(const int* __restrict__ counts, int* __restrict__ offsets) {
    if (threadIdx.x == 0) {
        int s = 0;
        for (int e = 0; e < Ec; e++) { offsets[e] = s; s += counts[e]; }
        offsets[Ec] = s;
    }
}

__global__ void k_fill(const int* __restrict__ tok_top, const int* __restrict__ offsets,
                       int* __restrict__ fill, int* __restrict__ slot_token,
                       int* __restrict__ slot_of) {
    int t = blockIdx.x * 256 + threadIdx.x;
    if (t >= Tc) return;
    #pragma unroll
    for (int j = 0; j < 2; j++) {
        int e = tok_top[t*2 + j];
        int pos = atomicAdd(&fill[e], 1);
        int slot = offsets[e] + pos;
        slot_token[slot] = t;
        slot_of[t*2 + j] = slot;
    }
}

// ---------------- GEMM1: HH = (X@W1+b1) * silu(X@W2+b2), per expert ----------------
// 256x128 tile, BK=32, 8 waves (4Mx2N), 64x64/wave/matrix.
// 3-stage LDS ring, 2-deep prefetch, counted vmcnt (never 0 in steady state),
// raw barriers (no vmcnt drain), setprio around MFMA, chunk-XOR swizzle (conflict-free).
#define BM1 256
#define BN1 128
#define A1SZ (BM1*BK)    // 8192 ushorts = 16KB
#define W1SZ (BN1*BK)    // 4096 ushorts = 8KB

__global__ __launch_bounds__(512, 2) void k_gemm1(
    const unsigned short* __restrict__ xbf,
    const unsigned short* __restrict__ w1t, const unsigned short* __restrict__ w2t,
    const float* __restrict__ b1, const float* __restrict__ b2,
    const int* __restrict__ counts, const int* __restrict__ offsets,
    const int* __restrict__ slot_token,
    unsigned short* __restrict__ hh) {
    int e = blockIdx.z;
    int n_e = counts[e];
    int m0 = blockIdx.y * BM1;
    if (m0 >= n_e) return;
    int base = offsets[e];
    int n0 = blockIdx.x * BN1;

    __shared__ __align__(16) unsigned short sA[3*A1SZ];    // 48KB
    __shared__ __align__(16) unsigned short sW1[3*W1SZ];   // 24KB
    __shared__ __align__(16) unsigned short sW2[3*W1SZ];   // 24KB
    __shared__ int tlist[BM1];

    int tid = threadIdx.x;
    if (tid < BM1) {
        int r = m0 + tid; if (r > n_e - 1) r = n_e - 1;    // pad tiles with a valid row
        tlist[tid] = slot_token[base + r];
    }
    __syncthreads();

    int wid = tid >> 6, lane = tid & 63;
    int wr = wid >> 1, wc = wid & 1;

    // staging: wave w -> A rows [w*32,w*32+32), W rows [w*16,w*16+16)
    int rl = lane >> 2, sc_ = lane & 3;
    int rA0 = wid*32 + rl, rA1 = rA0 + 16;
    int rB  = wid*16 + rl;
    int cA0 = sc_ ^ ((rA0 >> 1) & 3);
    int cA1 = sc_ ^ ((rA1 >> 1) & 3);
    int cB  = sc_ ^ ((rB  >> 1) & 3);
    int tA0 = tlist[rA0], tA1 = tlist[rA1];
    const unsigned short* pa0 = xbf + (size_t)tA0*Dc + cA0*8;
    const unsigned short* pa1 = xbf + (size_t)tA1*Dc + cA1*8;
    const size_t wb = ((size_t)e * Hc + n0) * Dc;
    const unsigned short* pw1 = w1t + wb + (size_t)rB*Dc + cB*8;
    const unsigned short* pw2 = w2t + wb + (size_t)rB*Dc + cB*8;
    int aofs = wid*1024, bofs = wid*512;

    f32x4 acc1[4][4], acc2[4][4];
    #pragma unroll
    for (int m = 0; m < 4; m++)
        #pragma unroll
        for (int n = 0; n < 4; n++)
            #pragma unroll
            for (int j = 0; j < 4; j++) { acc1[m][n][j] = 0.0f; acc2[m][n][j] = 0.0f; }

    int arow = lane & 15, cr = lane >> 4;

    auto STAGE_A = [&](int buf, int kk) {    // 2 loads
        unsigned short* d = sA + buf*A1SZ + aofs;
        gload16(pa0 + kk, d);
        gload16(pa1 + kk, d + 512);
    };
    auto STAGE_W = [&](int buf, int kk) {    // 2 loads
        gload16(pw1 + kk, sW1 + buf*W1SZ + bofs);
        gload16(pw2 + kk, sW2 + buf*W1SZ + bofs);
    };

    // prologue: tiles 0 and 1 in flight (8 loads)
    STAGE_A(0, 0);  STAGE_W(0, 0);
    STAGE_A(1, BK); STAGE_W(1, BK);

    const int NT = Dc / BK;   // 32
    int ib = 0;
    for (int t = 0; t < NT; ++t) {
        int is = ib + 2; if (is >= 3) is -= 3;
        if (t + 2 < NT) {
            STAGE_A(is, (t+2)*BK);                              // +2 in flight
            asm volatile("s_waitcnt vmcnt(6)" ::: "memory");    // tile t (4) drained
        } else if (t + 1 < NT) {
            asm volatile("s_waitcnt vmcnt(4)" ::: "memory");
        } else {
            asm volatile("s_waitcnt vmcnt(0)" ::: "memory");
        }
        fence_bar();                                            // BAR1: buffer ib ready for all
        const unsigned short* lA = sA  + ib*A1SZ;
        const unsigned short* l1 = sW1 + ib*W1SZ;
        const unsigned short* l2 = sW2 + ib*W1SZ;
        bf16x8 af[4], w1f[4], w2f[4];
        #pragma unroll
        for (int m = 0; m < 4; m++) {
            int rr = wr*64 + m*16 + arow;
            int cc = cr ^ ((rr >> 1) & 3);
            af[m] = *(const bf16x8*)&lA[rr*BK + cc*8];
        }
        #pragma unroll
        for (int n = 0; n < 4; n++) {
            int rr = wc*64 + n*16 + arow;
            int cc = cr ^ ((rr >> 1) & 3);
            w1f[n] = *(const bf16x8*)&l1[rr*BK + cc*8];
        }
        if (t + 2 < NT) STAGE_W(is, (t+2)*BK);                  // +2 in flight
        asm volatile("s_waitcnt lgkmcnt(0)" ::: "memory");      // A reads COMPLETE pre-BAR2
        fence_bar();                                            // BAR2
        __builtin_amdgcn_s_setprio(1);
        #pragma unroll
        for (int m = 0; m < 4; m++)
            #pragma unroll
            for (int n = 0; n < 4; n++)
                acc1[m][n] = __builtin_amdgcn_mfma_f32_16x16x32_bf16(af[m], w1f[n], acc1[m][n], 0, 0, 0);
        #pragma unroll
        for (int n = 0; n < 4; n++) {                           // W2 reads hide under MFMA1
            int rr = wc*64 + n*16 + arow;
            int cc = cr ^ ((rr >> 1) & 3);
            w2f[n] = *(const bf16x8*)&l2[rr*BK + cc*8];
        }
        #pragma unroll
        for (int m = 0; m < 4; m++)
            #pragma unroll
            for (int n = 0; n < 4; n++)
                acc2[m][n] = __builtin_amdgcn_mfma_f32_16x16x32_bf16(af[m], w2f[n], acc2[m][n], 0, 0, 0);
        __builtin_amdgcn_s_setprio(0);
        ib = ib + 1; if (ib == 3) ib = 0;
    }

    // epilogue: C/D layout col=lane&15, row=(lane>>4)*4+j
    int lrow = (lane >> 4) * 4, lcol = lane & 15;
    #pragma unroll
    for (int n = 0; n < 4; n++) {
        int hcol = n0 + wc*64 + n*16 + lcol;
        float bias1 = b1[e*Hc + hcol], bias2 = b2[e*Hc + hcol];
        #pragma unroll
        for (int m = 0; m < 4; m++) {
            int rb = m0 + wr*64 + m*16 + lrow;
            #pragma unroll
            for (int j = 0; j < 4; j++) {
                int r = rb + j;
                if (r < n_e) {
                    float h1v = acc1[m][n][j] + bias1;
                    float h2v = acc2[m][n][j] + bias2;
                    float hhv = h1v * (h2v / (1.0f + expf(-h2v)));   // h1 * silu(h2)
                    hh[(size_t)(base + r)*Hc + hcol] = f2bf(hhv);
                }
            }
        }
    }
}

// ---------------- GEMM2: OUT = HH @ Wp^T + bp, per expert ----------------
// 256x128 tile, K-step 64 as two BK=32 panels, 3-stage ring, counted vmcnt.
#define BM2 256
#define BN2 128
#define A2SZ (BM2*BK)    // per-panel 8192 ushorts
#define B2SZ (BN2*BK)    // per-panel 4096 ushorts

__global__ __launch_bounds__(512, 2) void k_gemm2(
    const unsigned short* __restrict__ hh,
    const unsigned short* __restrict__ wpt,
    const float* __restrict__ bp,
    const int* __restrict__ counts, const int* __restrict__ offsets,
    float* __restrict__ outb) {
    int e = blockIdx.z;
    int n_e = counts[e];
    int m0 = blockIdx.y * BM2;
    if (m0 >= n_e) return;
    int base = offsets[e];
    int n0 = blockIdx.x * BN2;

    __shared__ __align__(16) unsigned short sA[3*2*A2SZ];   // 96KB
    __shared__ __align__(16) unsigned short sB[3*2*B2SZ];   // 48KB

    int tid = threadIdx.x;
    int wid = tid >> 6, lane = tid & 63;
    int wr = wid >> 1, wc = wid & 1;

    int rl = lane >> 2, sc_ = lane & 3;
    int rA0 = wid*32 + rl, rA1 = rA0 + 16;
    int rB  = wid*16 + rl;
    int cA0 = sc_ ^ ((rA0 >> 1) & 3);
    int cA1 = sc_ ^ ((rA1 >> 1) & 3);
    int cB  = sc_ ^ ((rB  >> 1) & 3);
    int gr0 = m0 + rA0; if (gr0 > n_e - 1) gr0 = n_e - 1;
    int gr1 = m0 + rA1; if (gr1 > n_e - 1) gr1 = n_e - 1;
    const unsigned short* pa0 = hh + (size_t)(base + gr0)*Hc + cA0*8;
    const unsigned short* pa1 = hh + (size_t)(base + gr1)*Hc + cA1*8;
    const unsigned short* pb  = wpt + ((size_t)e*Dc + n0 + rB)*Hc + cB*8;
    int aofs = wid*1024, bofs = wid*512;

    f32x4 acc[4][4];
    #pragma unroll
    for (int m = 0; m < 4; m++)
        #pragma unroll
        for (int n = 0; n < 4; n++)
            #pragma unroll
            for (int j = 0; j < 4; j++) acc[m][n][j] = 0.0f;

    int arow = lane & 15, cr = lane >> 4;

    auto STAGE_A = [&](int buf, int kk) {    // 4 loads: 2 panels
        unsigned short* d = sA + buf*(2*A2SZ) + aofs;
        gload16(pa0 + kk, d);            gload16(pa1 + kk, d + 512);
        gload16(pa0 + kk + BK, d + A2SZ); gload16(pa1 + kk + BK, d + A2SZ + 512);
    };
    auto STAGE_B = [&](int buf, int kk) {    // 2 loads: 2 panels
        unsigned short* d = sB + buf*(2*B2SZ) + bofs;
        gload16(pb + kk, d);
        gload16(pb + kk + BK, d + B2SZ);
    };

    STAGE_A(0, 0);  STAGE_B(0, 0);
    STAGE_A(1, 64); STAGE_B(1, 64);

    const int NT = Hc / 64;   // 64 iterations of K=64
    int ib = 0;
    for (int t = 0; t < NT; ++t) {
        int is = ib + 2; if (is >= 3) is -= 3;
        if (t + 2 < NT) {
            STAGE_A(is, (t+2)*64);                               // +4 in flight (16 total)
            asm volatile("s_waitcnt vmcnt(10)" ::: "memory");    // tile t (6) drained
        } else if (t + 1 < NT) {
            asm volatile("s_waitcnt vmcnt(6)" ::: "memory");
        } else {
            asm volatile("s_waitcnt vmcnt(0)" ::: "memory");
        }
        fence_bar();                                             // BAR1
        const unsigned short* lA0 = sA + ib*(2*A2SZ);
        const unsigned short* lA1 = lA0 + A2SZ;
        const unsigned short* lB0 = sB + ib*(2*B2SZ);
        const unsigned short* lB1 = lB0 + B2SZ;
        bf16x8 af[2][4], wf[2][4];
        #pragma unroll
        for (int m = 0; m < 4; m++) {
            int rr = wr*64 + m*16 + arow;
            int cc = cr ^ ((rr >> 1) & 3);
            af[0][m] = *(const bf16x8*)&lA0[rr*BK + cc*8];
            af[1][m] = *(const bf16x8*)&lA1[rr*BK + cc*8];
        }
        #pragma unroll
        for (int n = 0; n < 4; n++) {
            int rr = wc*64 + n*16 + arow;
            int cc = cr ^ ((rr >> 1) & 3);
            wf[0][n] = *(const bf16x8*)&lB0[rr*BK + cc*8];
        }
        if (t + 2 < NT) STAGE_B(is, (t+2)*64);                   // +2 in flight
        asm volatile("s_waitcnt lgkmcnt(0)" ::: "memory");       // A reads COMPLETE pre-BAR2
        fence_bar();                                             // BAR2
        __builtin_amdgcn_s_setprio(1);
        #pragma unroll
        for (int m = 0; m < 4; m++)
            #pragma unroll
            for (int n = 0; n < 4; n++)
                acc[m][n] = __builtin_amdgcn_mfma_f32_16x16x32_bf16(af[0][m], wf[0][n], acc[m][n], 0, 0, 0);
        #pragma unroll
        for (int n = 0; n < 4; n++) {                            // panel-1 B reads hide under MFMA
            int rr = wc*64 + n*16 + arow;
            int cc = cr ^ ((rr >> 1) & 3);
            wf[1][n] = *(const bf16x8*)&lB1[rr*BK + cc*8];
        }
        #pragma unroll
        for (int m = 0; m < 4; m++)
            #pragma unroll
            for (int n = 0; n < 4; n++)
                acc[m][n] = __builtin_amdgcn_mfma_f32_16x16x32_bf16(af[1][m], wf[1][n], acc[m][n], 0, 0, 0);
        __builtin_amdgcn_s_setprio(0);
        ib = ib + 1; if (ib == 3) ib = 0;
    }

    int lrow = (lane >> 4) * 4, lcol = lane & 15;
    #pragma unroll
    for (int n = 0; n < 4; n++) {
        int dcol = n0 + wc*64 + n*16 + lcol;
        float bias = bp[e*Dc + dcol];
        #pragma unroll
        for (int m = 0; m < 4; m++) {
            int rb = m0 + wr*64 + m*16 + lrow;
            #pragma unroll
            for (int j = 0; j < 4; j++) {
                int r = rb + j;
                if (r < n_e)
                    outb[(size_t)(base + r)*Dc + dcol] = acc[m][n][j] + bias;
            }
        }
    }
}

// ---------------- combine: final[t] = w0*OUT[s0] + w1*OUT[s1] ----------------
__global__ void k_combine(const float* __restrict__ outb, const int* __restrict__ slot_of,
                          const float* __restrict__ tok_w, float* __restrict__ final_out) {
    int gid = blockIdx.x * 256 + threadIdx.x;   // Tc*Dc/4 threads
    int t = gid >> 8;
    int c = (gid & 255) * 4;
    int s0 = slot_of[t*2], s1 = slot_of[t*2 + 1];
    float w0 = tok_w[t*2], w1 = tok_w[t*2 + 1];
    float4 o0 = *(const float4*)&outb[(size_t)s0*Dc + c];
    float4 o1 = *(const float4*)&outb[(size_t)s1*Dc + c];
    float4 r;
    r.x = w0*o0.x + w1*o1.x;
    r.y = w0*o0.y + w1*o1.y;
    r.z = w0*o0.z + w1*o1.z;
    r.w = w0*o0.w + w1*o1.w;
    *(float4*)&final_out[(size_t)t*Dc + c] = r;
}

extern "C" void kernel_launch(void* const* d_in, const int* in_sizes, int n_in,
                              void* d_out, int out_size, void* d_ws, size_t ws_size,
                              hipStream_t stream) {
    (void)in_sizes; (void)n_in; (void)out_size; (void)ws_size;
    const float* x     = (const float*)d_in[0];
    const float* noise = (const float*)d_in[1];
    const float* Wg    = (const float*)d_in[2];
    const float* nw    = (const float*)d_in[3];
    const float* W1    = (const float*)d_in[4];
    const float* b1    = (const float*)d_in[5];
    const float* W2    = (const float*)d_in[6];
    const float* b2    = (const float*)d_in[7];
    const float* Wp    = (const float*)d_in[8];
    const float* bp    = (const float*)d_in[9];

    char* ws = (char*)d_ws;
    size_t off = 0;
    unsigned short* XBF = (unsigned short*)(ws + off); off += (size_t)Tc*Dc*2;       // 8 MB
    unsigned short* W1T = (unsigned short*)(ws + off); off += (size_t)Ec*Dc*Hc*2;    // 64 MB
    unsigned short* W2T = (unsigned short*)(ws + off); off += (size_t)Ec*Dc*Hc*2;    // 64 MB
    unsigned short* WPT = (unsigned short*)(ws + off); off += (size_t)Ec*Hc*Dc*2;    // 64 MB
    unsigned short* HH  = (unsigned short*)(ws + off); off += (size_t)NSLOT*Hc*2;    // 64 MB
    float*          OUTB= (float*)(ws + off);          off += (size_t)NSLOT*Dc*4;    // 32 MB
    int*   counts    = (int*)(ws + off);
    int*   fill      = (int*)(ws + off + 32);
    int*   offsets   = (int*)(ws + off + 64);
    int*   tok_top   = (int*)(ws + off + 128);
    float* tok_w     = (float*)(ws + off + 128 + (size_t)Tc*2*4);
    int*   slot_token= (int*)(ws + off + 128 + (size_t)Tc*2*8);
    int*   slot_of   = (int*)(ws + off + 128 + (size_t)Tc*2*8 + (size_t)NSLOT*4);

    float* final_out = (float*)d_out;
    float* idx_out   = (float*)d_out + FINAL_N;

    hipMemsetAsync(counts, 0, 64, stream);   // counts + fill

    k_cvt_x<<<(Tc*Dc/8)/256, 256, 0, stream>>>(x, XBF);
    // W1 + W2 transposes in one launch (z = 16: [0,8) -> W1, [8,16) -> W2)
    k_transpose_cvt2<<<dim3(Hc/64, Dc/64, 2*Ec), 256, 0, stream>>>(W1, W2, W1T, W2T, Dc, Hc, Ec);
    k_transpose_cvt2<<<dim3(Dc/64, Hc/64, Ec), 256, 0, stream>>>(Wp, Wp, WPT, WPT, Hc, Dc, Ec);

    k_gate<<<Tc, 64, 0, stream>>>(x, noise, Wg, nw, idx_out, counts, tok_top, tok_w);
    k_scan<<<1, 64, 0, stream>>>(counts, offsets);
    k_fill<<<Tc/256, 256, 0, stream>>>(tok_top, offsets, fill, slot_token, slot_of);

    k_gemm1<<<dim3(Hc/BN1, Tc/BM1, Ec), 512, 0, stream>>>(XBF, W1T, W2T, b1, b2,
                                                          counts, offsets, slot_token, HH);
    k_gemm2<<<dim3(Dc/BN2, Tc/BM2, Ec), 512, 0, stream>>>(HH, WPT, bp, counts, offsets, OUTB);
    k_combine<<<(Tc*Dc/4)/256, 256, 0, stream>>>(OUTB, slot_of, tok_w, final_out);
}